// Round 13
// baseline (171.375 us; speedup 1.0000x reference)
//
#include <hip/hip_runtime.h>
#include <cstdint>
#include <cstddef>

typedef unsigned short u16;
typedef __attribute__((ext_vector_type(8))) short bf16x8;
typedef __attribute__((ext_vector_type(4))) float f32x4;
typedef __attribute__((ext_vector_type(16))) float f32x16;
typedef __attribute__((ext_vector_type(4))) uint32_t u32x4;

#define DEV __device__ __forceinline__

static constexpr float LOG2E = 1.4426950408889634f;

DEV u16 f2bf(float f) {
  uint32_t u = __float_as_uint(f);
  u += 0x7fffu + ((u >> 16) & 1u);
  return (u16)(u >> 16);
}
DEV float bf2f(u16 h) {
  uint32_t u = ((uint32_t)h) << 16;
  return __uint_as_float(u);
}
// packed f32x2 -> bf16x2 (RNE), single VOP3 instr
DEV uint32_t cvtpk(float lo, float hi) {
  uint32_t r;
  asm("v_cvt_pk_bf16_f32 %0, %1, %2" : "=v"(r) : "v"(lo), "v"(hi));
  return r;
}
// 2^x via v_exp_f32 (native exp2)
DEV float exp2fast(float x) {
  float r;
  asm("v_exp_f32 %0, %1" : "=v"(r) : "v"(x));
  return r;
}
// swap a[lanes 32..63] <-> b[lanes 0..31]
DEV void plswap(uint32_t& a, uint32_t& b) {
  asm("v_permlane32_swap_b32 %0, %1" : "+v"(a), "+v"(b));
}

DEV f32x4 mfma16(bf16x8 a, bf16x8 b, f32x4 c) {
  return __builtin_amdgcn_mfma_f32_16x16x32_bf16(a, b, c, 0, 0, 0);
}
DEV f32x16 mfma32(bf16x8 a, bf16x8 b, f32x16 c) {
  return __builtin_amdgcn_mfma_f32_32x32x16_bf16(a, b, c, 0, 0, 0);
}

// async global->LDS, 16B per lane; lds ptr must be wave-uniform
DEV void gload_lds16(const void* g, void* l) {
  __builtin_amdgcn_global_load_lds(
      (const __attribute__((address_space(1))) uint32_t*)g,
      (__attribute__((address_space(3))) uint32_t*)l, 16, 0, 0);
}

static constexpr int BATCH = 4;
static constexpr int C = 256;    // in/out channels
static constexpr int CI = 128;   // inter channels
static constexpr int N = 4096;   // tokens (64x64)

// ---------------- weight convert (q_w pre-scaled by log2e) -----------------
__global__ __launch_bounds__(256) void cvt_w(const float* __restrict__ a,
                                             const float* __restrict__ b,
                                             const float* __restrict__ c,
                                             const float* __restrict__ d,
                                             u16* __restrict__ oa, u16* __restrict__ ob,
                                             u16* __restrict__ oc, u16* __restrict__ od) {
  int i = blockIdx.x * 256 + threadIdx.x;
  oa[i] = f2bf(a[i] * LOG2E);  // Q weights carry the log2e softmax scale
  ob[i] = f2bf(b[i]);
  oc[i] = f2bf(c[i]);
  od[i] = f2bf(d[i]);
}

// ---------------- QKV projection (R10 64-token form; revert of R12) --------
__global__ __launch_bounds__(256) void proj_kernel(
    const float* __restrict__ x, const float* __restrict__ rgbd,
    const u16* __restrict__ Wq, const u16* __restrict__ Wk, const u16* __restrict__ Wv,
    const float* __restrict__ qb, const float* __restrict__ kb, const float* __restrict__ vb,
    u16* __restrict__ Qb, u16* __restrict__ Kb, u16* __restrict__ Vtb) {
  __shared__ __align__(16) u16 xT[64][C + 8];
  __shared__ __align__(16) u16 rT[64][C + 8];
  const int b = blockIdx.y;
  const int n0 = blockIdx.x * 64;
  const int t = threadIdx.x;
  {
    const int tok = t & 63, cp = (t >> 6) * 2;
    const float* xb = x + (size_t)b * C * N + n0;
    const float* rb = rgbd + (size_t)b * C * N + n0;
    for (int c0 = 0; c0 < C; c0 += 8) {
      int c = c0 + cp;
      *(uint32_t*)&xT[tok][c] = cvtpk(xb[(size_t)c * N + tok], xb[(size_t)(c + 1) * N + tok]);
      *(uint32_t*)&rT[tok][c] = cvtpk(rb[(size_t)c * N + tok], rb[(size_t)(c + 1) * N + tok]);
    }
  }
  __syncthreads();
  const int w = t >> 6, lane = t & 63, g = lane >> 4, cl = lane & 15;

#define PROJ_QK(Sarr, W, bias, Out, SCL)                                              \
  {                                                                                   \
    bf16x8 afr[8];                                                                    \
    _Pragma("unroll") for (int ks = 0; ks < 8; ++ks)                                  \
        afr[ks] = *(const bf16x8*)&Sarr[w * 16 + cl][ks * 32 + g * 8];                \
    _Pragma("unroll") for (int ct = 0; ct < 8; ++ct) {                                \
      f32x4 acc = {0.f, 0.f, 0.f, 0.f};                                               \
      _Pragma("unroll") for (int ks = 0; ks < 8; ++ks) {                              \
        bf16x8 bb = *(const bf16x8*)&W[(size_t)(ct * 16 + cl) * C + ks * 32 + g * 8]; \
        acc = mfma16(afr[ks], bb, acc);                                               \
      }                                                                               \
      float bv = bias[ct * 16 + cl] * (SCL);                                          \
      _Pragma("unroll") for (int r = 0; r < 4; ++r) {                                 \
        int tok = n0 + w * 16 + g * 4 + r;                                            \
        Out[((size_t)b * N + tok) * CI + ct * 16 + cl] = f2bf(acc[r] + bv);           \
      }                                                                               \
    }                                                                                 \
  }

  PROJ_QK(xT, Wq, qb, Qb, LOG2E)
  PROJ_QK(rT, Wk, kb, Kb, 1.0f)
#undef PROJ_QK

  #pragma unroll
  for (int rt = 0; rt < 2; ++rt) {
    bf16x8 aw[8];
    #pragma unroll
    for (int ks = 0; ks < 8; ++ks)
      aw[ks] = *(const bf16x8*)&Wv[(size_t)(w * 32 + rt * 16 + cl) * C + ks * 32 + g * 8];
    #pragma unroll
    for (int ct = 0; ct < 4; ++ct) {
      f32x4 acc = {0.f, 0.f, 0.f, 0.f};
      #pragma unroll
      for (int ks = 0; ks < 8; ++ks) {
        bf16x8 bb = *(const bf16x8*)&rT[ct * 16 + cl][ks * 32 + g * 8];
        acc = mfma16(aw[ks], bb, acc);
      }
      #pragma unroll
      for (int r = 0; r < 4; ++r) {
        int o = w * 32 + rt * 16 + g * 4 + r;
        Vtb[((size_t)b * CI + o) * N + n0 + ct * 16 + cl] = f2bf(acc[r] + vb[o]);
      }
    }
  }
}

// ---------------- flash attention: split-8, 4 blocks/CU, NT stores ---------
// R9's kernel (32-key tiles, 32KB LDS, (256,4), 43% occupancy) with the one
// change that tests the write-pollution hypothesis: ALL Opart/ml stores are
// nontemporal (no L2 write-allocate). R9's FETCH=267MB/WRITE=78MB showed L2
// thrash from scattered 2B stores across 1024 concurrent blocks; K/V read
// working set (~1MB/XCD) fits L2 fine. If writes stop polluting, the 43%
// occupancy finally pays.
template <int SPL>
__global__ __launch_bounds__(256, 4) void attn_kernel(
    const u16* __restrict__ Qb, const u16* __restrict__ Kb,
    const u16* __restrict__ Vtb, u16* __restrict__ Opart,
    float2* __restrict__ ml) {
  constexpr int KPB = N / SPL;
  constexpr int NT = KPB / 32;
  constexpr int CPX = 16 * SPL;  // blocks per XCD
  __shared__ __align__(16) u16 Klds[2][32 * 128];  // [key][ci], swizzled chunks
  __shared__ __align__(16) u16 Vlds[2][128 * 32];  // [ci][key], swizzled chunks
  const int lin = blockIdx.x;
  const int nl = (lin & 7) * CPX + (lin >> 3);
  const int qi = nl & 31;
  const int grp = nl >> 5;  // b + 4*s
  const int b = grp & 3;
  const int s = grp >> 2;
  const int q0 = qi * 128;
  const int t = threadIdx.x;
  const int w = t >> 6, lane = t & 63;
  const int hi = lane >> 5, l31 = lane & 31;

  const u16* Kg = Kb + (size_t)b * N * CI;
  const u16* Vg = Vtb + (size_t)b * CI * N;

  // staging source mappings (chunk = 16B), inverse XOR swizzle
  const int k_r = t >> 4;                      // 0..15 (row within segment)
  const int k_ss = (t & 15) ^ k_r;             // K: c ^ (key&15)
  const int v_r = t >> 2;                      // 0..63 (ci within segment)
  const int v_ss = (t & 3) ^ ((t >> 3) & 3);   // V: c ^ ((ci>>1)&3)
  const int wbase = (t & ~63);

#define STAGE_K(bi, k0_)                                                          \
  do {                                                                            \
    _Pragma("unroll") for (int c = 0; c < 2; ++c) {                               \
      gload_lds16(Kg + (size_t)((k0_) + c * 16 + k_r) * CI + k_ss * 8,            \
                  &Klds[bi][(c * 256 + wbase) * 8]);                              \
    }                                                                             \
  } while (0)
#define STAGE_V(bi, k0_)                                                          \
  do {                                                                            \
    _Pragma("unroll") for (int c = 0; c < 2; ++c) {                               \
      gload_lds16(Vg + (size_t)(c * 64 + v_r) * N + (k0_) + v_ss * 8,             \
                  &Vlds[bi][(c * 256 + wbase) * 8]);                              \
    }                                                                             \
  } while (0)

  // hoisted Q B-fragments: lane holds Q[q0+w*32+l31][ci 16m+8hi .. +7]
  const u16* Qg = Qb + ((size_t)b * N + q0 + w * 32 + l31) * CI;
  bf16x8 qf[8];
  #pragma unroll
  for (int mm = 0; mm < 8; ++mm)
    qf[mm] = *(const bf16x8*)(Qg + mm * 16 + hi * 8);
  asm volatile("s_waitcnt vmcnt(0)" ::: "memory");

  f32x16 oacc[4];
  #pragma unroll
  for (int ct = 0; ct < 4; ++ct)
    #pragma unroll
    for (int i = 0; i < 16; ++i) oacc[ct][i] = 0.f;
  float m_run = -1e30f, l_run = 0.f;

  const int kbeg = s * KPB;
  STAGE_K(0, kbeg);
  STAGE_V(0, kbeg);
  STAGE_K(1, kbeg + 32);
  STAGE_V(1, kbeg + 32);

  int buf = 0;
  for (int tt = 0; tt < NT; ++tt) {
    asm volatile("s_waitcnt vmcnt(4)" ::: "memory");
    __builtin_amdgcn_s_barrier();
    const int knext = kbeg + ((tt + 2 < NT) ? tt + 2 : tt) * 32;  // dummy tail restage

    // ---- K phase: A-frags K[key=l31][ci 16m+8hi ..+7], swizzled chunk ----
    bf16x8 kf[8];
    #pragma unroll
    for (int mm = 0; mm < 8; ++mm)
      kf[mm] = *(const bf16x8*)&Klds[buf][l31 * 128 + ((((mm << 1) | hi) ^ l31) & 15) * 8];
    asm volatile("s_waitcnt lgkmcnt(0)" ::: "memory");
    __builtin_amdgcn_sched_barrier(0);
    __builtin_amdgcn_s_barrier();
    STAGE_K(buf, knext);

    // ---- QK^T: S^T[key][q] = mfma32(K, Q), K-dim = 128 ci over 8 mfma ----
    f32x16 st;
    #pragma unroll
    for (int i = 0; i < 16; ++i) st[i] = 0.f;
    __builtin_amdgcn_s_setprio(1);
    #pragma unroll
    for (int mm = 0; mm < 8; ++mm) st = mfma32(kf[mm], qf[mm], st);
    __builtin_amdgcn_s_setprio(0);

    // ---- online softmax: lane owns q = l31; 16 key-slots in-lane ----
    float tmax = st[0];
    #pragma unroll
    for (int i = 1; i < 16; ++i) tmax = fmaxf(tmax, st[i]);
    tmax = fmaxf(tmax, __shfl_xor(tmax, 32));
    if (!__all(tmax - m_run <= 11.5f)) {
      const float mn = fmaxf(m_run, tmax);
      const float alpha = exp2fast(m_run - mn);
      m_run = mn;
      l_run *= alpha;
      #pragma unroll
      for (int reg = 0; reg < 16; ++reg) {
        float ar = __shfl(alpha, (reg & 3) + 8 * (reg >> 2) + 4 * hi);
        oacc[0][reg] *= ar; oacc[1][reg] *= ar;
        oacc[2][reg] *= ar; oacc[3][reg] *= ar;
      }
    }
    float p[16];
    float ls = 0.f;
    #pragma unroll
    for (int i = 0; i < 16; ++i) {
      p[i] = exp2fast(st[i] - m_run);
      ls += p[i];
    }
    ls += __shfl_xor(ls, 32);
    l_run += ls;

    // ---- P -> PV A-fragment in-register (cvtpk + permlane32_swap) ----
    uint32_t d0 = cvtpk(p[0], p[1]),   e0 = cvtpk(p[4], p[5]);
    uint32_t d1 = cvtpk(p[2], p[3]),   e1 = cvtpk(p[6], p[7]);
    uint32_t d2 = cvtpk(p[8], p[9]),   e2 = cvtpk(p[12], p[13]);
    uint32_t d3 = cvtpk(p[10], p[11]), e3 = cvtpk(p[14], p[15]);
    plswap(d0, e0);
    plswap(d1, e1);
    plswap(d2, e2);
    plswap(d3, e3);
    u32x4 pw0 = {d0, d1, e0, e1};  // keys 16*0 + 8hi ..
    u32x4 pw1 = {d2, d3, e2, e3};  // keys 16*1 + 8hi ..
    bf16x8 pa0 = __builtin_bit_cast(bf16x8, pw0);
    bf16x8 pa1 = __builtin_bit_cast(bf16x8, pw1);

    // ---- V phase: B-frags V[key 16ks+8hi ..+7][ci=32ct+l31] ----
    bf16x8 vf[4][2];
    const int vsw = (l31 >> 1) & 3;
    #pragma unroll
    for (int ct = 0; ct < 4; ++ct)
      #pragma unroll
      for (int ks = 0; ks < 2; ++ks)
        vf[ct][ks] = *(const bf16x8*)
            &Vlds[buf][(32 * ct + l31) * 32 + ((((ks << 1) | hi) ^ vsw) & 3) * 8];
    asm volatile("s_waitcnt lgkmcnt(0)" ::: "memory");
    __builtin_amdgcn_sched_barrier(0);
    __builtin_amdgcn_s_barrier();
    STAGE_V(buf, knext);

    // ---- PV: O[q][ci] += P x V ----
    __builtin_amdgcn_s_setprio(1);
    #pragma unroll
    for (int ct = 0; ct < 4; ++ct) {
      oacc[ct] = mfma32(pa0, vf[ct][0], oacc[ct]);
      oacc[ct] = mfma32(pa1, vf[ct][1], oacc[ct]);
    }
    __builtin_amdgcn_s_setprio(0);

    buf ^= 1;
  }
#undef STAGE_K
#undef STAGE_V
  asm volatile("s_waitcnt vmcnt(0)" ::: "memory");  // drain dummy restages

  // epilogue: normalized partial O + (m,l), ALL NONTEMPORAL (no L2 allocate)
  const float inv = 1.0f / l_run;
  #pragma unroll
  for (int reg = 0; reg < 16; ++reg) {
    const int ql = (reg & 3) + 8 * (reg >> 2) + 4 * hi;
    const float invr = __shfl(inv, ql);
    const int q = q0 + w * 32 + ql;
    #pragma unroll
    for (int ct = 0; ct < 4; ++ct)
      __builtin_nontemporal_store(
          (u16)f2bf(oacc[ct][reg] * invr),
          &Opart[(((size_t)(s * BATCH + b)) * N + q) * CI + 32 * ct + l31]);
  }
  if (lane < 32) {
    const int q = q0 + w * 32 + lane;
    float2* mp = &ml[(size_t)(s * BATCH + b) * N + q];
    __builtin_nontemporal_store(m_run, &mp->x);
    __builtin_nontemporal_store(l_run, &mp->y);
  }
}

// ---------------- fused combine + output projection + residual -------------
template <int NS>
__global__ __launch_bounds__(256) void outproj_kernel(
    const u16* __restrict__ Opart, const float2* __restrict__ ml,
    const u16* __restrict__ Wo, const float* __restrict__ obias,
    const float* __restrict__ rgbd, float* __restrict__ out) {
  __shared__ __align__(16) u16 ObL[64][CI + 8];
  const int b = blockIdx.y;
  const int n0 = blockIdx.x * 64;
  const int t = threadIdx.x;

  // ---- phase A: split-K combine into LDS ----
  #pragma unroll
  for (int i = 0; i < 4; ++i) {
    const int idx = t + i * 256;          // over 64 rows x 16 ci-chunks
    const int row_l = idx >> 4, ci8 = idx & 15;
    const size_t row = (size_t)b * N + n0 + row_l;
    float2 sv[NS];
    float M = -1e30f;
    #pragma unroll
    for (int sp = 0; sp < NS; ++sp) {
      sv[sp] = ml[(size_t)sp * BATCH * N + row];
      M = fmaxf(M, sv[sp].x);
    }
    float wv[NS], wsum = 0.f;
    #pragma unroll
    for (int sp = 0; sp < NS; ++sp) {
      wv[sp] = sv[sp].y * exp2fast(sv[sp].x - M);
      wsum += wv[sp];
    }
    const float invL = 1.0f / wsum;
    float acc[8];
    #pragma unroll
    for (int j = 0; j < 8; ++j) acc[j] = 0.f;
    #pragma unroll
    for (int sp = 0; sp < NS; ++sp) {
      const float wsc = wv[sp] * invL;
      bf16x8 v = *(const bf16x8*)&Opart[((size_t)sp * BATCH * N + row) * CI + ci8 * 8];
      #pragma unroll
      for (int j = 0; j < 8; ++j) acc[j] += wsc * bf2f((u16)v[j]);
    }
    bf16x8 o;
    #pragma unroll
    for (int j = 0; j < 8; ++j) o[j] = (short)f2bf(acc[j]);
    *(bf16x8*)&ObL[row_l][ci8 * 8] = o;
  }
  __syncthreads();

  // ---- phase B: out-projection MFMA + bias + residual ----
  const int w = t >> 6, lane = t & 63, g = lane >> 4, cl = lane & 15;
  f32x4 acc[4][4];
  #pragma unroll
  for (int i = 0; i < 4; ++i)
    #pragma unroll
    for (int j = 0; j < 4; ++j) acc[i][j] = {0.f, 0.f, 0.f, 0.f};

  #pragma unroll
  for (int ks = 0; ks < 4; ++ks) {
    bf16x8 bo[4];
    #pragma unroll
    for (int ct = 0; ct < 4; ++ct)
      bo[ct] = *(const bf16x8*)&ObL[ct * 16 + cl][ks * 32 + g * 8];
    #pragma unroll
    for (int rt = 0; rt < 4; ++rt) {
      bf16x8 aw = *(const bf16x8*)&Wo[(size_t)(w * 64 + rt * 16 + cl) * CI + ks * 32 + g * 8];
      #pragma unroll
      for (int ct = 0; ct < 4; ++ct) acc[rt][ct] = mfma16(aw, bo[ct], acc[rt][ct]);
    }
  }
  #pragma unroll
  for (int rt = 0; rt < 4; ++rt) {
    #pragma unroll
    for (int r = 0; r < 4; ++r) {
      const int o = w * 64 + rt * 16 + g * 4 + r;
      const float bb = obias[o];
      #pragma unroll
      for (int ct = 0; ct < 4; ++ct) {
        size_t idx = ((size_t)b * C + o) * N + n0 + ct * 16 + cl;
        out[idx] = rgbd[idx] + bb + acc[rt][ct][r];
      }
    }
  }
}

// ---------------- launch ----------------------------------------------------
extern "C" void kernel_launch(void* const* d_in, const int* in_sizes, int n_in,
                              void* d_out, int out_size, void* d_ws, size_t ws_size,
                              hipStream_t stream) {
  (void)in_sizes; (void)n_in; (void)out_size;
  const float* rgbd = (const float*)d_in[0];
  const float* x    = (const float*)d_in[1];
  const float* q_w  = (const float*)d_in[2];
  const float* q_b  = (const float*)d_in[3];
  const float* k_w  = (const float*)d_in[4];
  const float* k_b  = (const float*)d_in[5];
  const float* v_w  = (const float*)d_in[6];
  const float* v_b  = (const float*)d_in[7];
  const float* o_w  = (const float*)d_in[8];
  const float* o_b  = (const float*)d_in[9];
  float* out = (float*)d_out;

  char* ws = (char*)d_ws;
  const size_t MB = 1024 * 1024;
  const size_t szQKV = (size_t)BATCH * N * CI * sizeof(u16);  // 4 MB each
  u16* Qb  = (u16*)(ws);                      // 0..4MB
  u16* Kb  = (u16*)(ws + szQKV);              // 4..8MB
  u16* Vtb = (u16*)(ws + 2 * szQKV);          // 8..12MB
  u16* Wq  = (u16*)(ws + 3 * szQKV);          // 12..12.25MB
  u16* Wk  = Wq + (size_t)CI * C;
  u16* Wv  = Wk + (size_t)CI * C;
  u16* Wo  = Wv + (size_t)CI * C;
  u16* Opart = (u16*)(ws + 13 * MB);
  // split=8 needs 13 + 8*4 + 1 = 46MB of ws; fall back to 4 if tight
  const int split = (ws_size >= 46 * MB) ? 8 : 4;
  float2* ml = (float2*)(ws + 13 * MB + (size_t)split * szQKV);

  cvt_w<<<dim3((C * CI) / 256), 256, 0, stream>>>(q_w, k_w, v_w, o_w, Wq, Wk, Wv, Wo);
  proj_kernel<<<dim3(N / 64, BATCH), 256, 0, stream>>>(x, rgbd, Wq, Wk, Wv,
                                                       q_b, k_b, v_b, Qb, Kb, Vtb);
  if (split == 8) {
    attn_kernel<8><<<dim3(128 * 8), 256, 0, stream>>>(Qb, Kb, Vtb, Opart, ml);
    outproj_kernel<8><<<dim3(N / 64, BATCH), 256, 0, stream>>>(Opart, ml, Wo, o_b, rgbd, out);
  } else {
    attn_kernel<4><<<dim3(128 * 4), 256, 0, stream>>>(Qb, Kb, Vtb, Opart, ml);
    outproj_kernel<4><<<dim3(N / 64, BATCH), 256, 0, stream>>>(Opart, ml, Wo, o_b, rgbd, out);
  }
}

// Round 14
// 86.876 us; speedup vs baseline: 1.9726x; 1.9726x over previous
//
#include <hip/hip_runtime.h>
#include <cstdint>
#include <cstddef>

typedef unsigned short u16;
typedef __attribute__((ext_vector_type(8))) short bf16x8;
typedef __attribute__((ext_vector_type(4))) float f32x4;
typedef __attribute__((ext_vector_type(16))) float f32x16;
typedef __attribute__((ext_vector_type(4))) uint32_t u32x4;

#define DEV __device__ __forceinline__

static constexpr float LOG2E = 1.4426950408889634f;

DEV u16 f2bf(float f) {
  uint32_t u = __float_as_uint(f);
  u += 0x7fffu + ((u >> 16) & 1u);
  return (u16)(u >> 16);
}
DEV float bf2f(u16 h) {
  uint32_t u = ((uint32_t)h) << 16;
  return __uint_as_float(u);
}
// packed f32x2 -> bf16x2 (RNE), single VOP3 instr
DEV uint32_t cvtpk(float lo, float hi) {
  uint32_t r;
  asm("v_cvt_pk_bf16_f32 %0, %1, %2" : "=v"(r) : "v"(lo), "v"(hi));
  return r;
}
// 2^x via v_exp_f32 (native exp2)
DEV float exp2fast(float x) {
  float r;
  asm("v_exp_f32 %0, %1" : "=v"(r) : "v"(x));
  return r;
}
// swap a[lanes 32..63] <-> b[lanes 0..31]
DEV void plswap(uint32_t& a, uint32_t& b) {
  asm("v_permlane32_swap_b32 %0, %1" : "+v"(a), "+v"(b));
}

DEV f32x4 mfma16(bf16x8 a, bf16x8 b, f32x4 c) {
  return __builtin_amdgcn_mfma_f32_16x16x32_bf16(a, b, c, 0, 0, 0);
}
DEV f32x16 mfma32(bf16x8 a, bf16x8 b, f32x16 c) {
  return __builtin_amdgcn_mfma_f32_32x32x16_bf16(a, b, c, 0, 0, 0);
}

// async global->LDS, 16B per lane; lds ptr must be wave-uniform
DEV void gload_lds16(const void* g, void* l) {
  __builtin_amdgcn_global_load_lds(
      (const __attribute__((address_space(1))) uint32_t*)g,
      (__attribute__((address_space(3))) uint32_t*)l, 16, 0, 0);
}

static constexpr int BATCH = 4;
static constexpr int C = 256;    // in/out channels
static constexpr int CI = 128;   // inter channels
static constexpr int N = 4096;   // tokens (64x64)
static constexpr int SPLIT = 4;  // key-range split (L2-constrained optimum)

// ---------------- weight convert (q_w pre-scaled by log2e) -----------------
__global__ __launch_bounds__(256) void cvt_w(const float* __restrict__ a,
                                             const float* __restrict__ b,
                                             const float* __restrict__ c,
                                             const float* __restrict__ d,
                                             u16* __restrict__ oa, u16* __restrict__ ob,
                                             u16* __restrict__ oc, u16* __restrict__ od) {
  int i = blockIdx.x * 256 + threadIdx.x;
  oa[i] = f2bf(a[i] * LOG2E);  // Q weights carry the log2e softmax scale
  ob[i] = f2bf(b[i]);
  oc[i] = f2bf(c[i]);
  od[i] = f2bf(d[i]);
}

// ---------------- QKV projection (R10 64-token form; known good) -----------
__global__ __launch_bounds__(256) void proj_kernel(
    const float* __restrict__ x, const float* __restrict__ rgbd,
    const u16* __restrict__ Wq, const u16* __restrict__ Wk, const u16* __restrict__ Wv,
    const float* __restrict__ qb, const float* __restrict__ kb, const float* __restrict__ vb,
    u16* __restrict__ Qb, u16* __restrict__ Kb, u16* __restrict__ Vtb) {
  __shared__ __align__(16) u16 xT[64][C + 8];
  __shared__ __align__(16) u16 rT[64][C + 8];
  const int b = blockIdx.y;
  const int n0 = blockIdx.x * 64;
  const int t = threadIdx.x;
  {
    const int tok = t & 63, cp = (t >> 6) * 2;
    const float* xb = x + (size_t)b * C * N + n0;
    const float* rb = rgbd + (size_t)b * C * N + n0;
    for (int c0 = 0; c0 < C; c0 += 8) {
      int c = c0 + cp;
      *(uint32_t*)&xT[tok][c] = cvtpk(xb[(size_t)c * N + tok], xb[(size_t)(c + 1) * N + tok]);
      *(uint32_t*)&rT[tok][c] = cvtpk(rb[(size_t)c * N + tok], rb[(size_t)(c + 1) * N + tok]);
    }
  }
  __syncthreads();
  const int w = t >> 6, lane = t & 63, g = lane >> 4, cl = lane & 15;

#define PROJ_QK(Sarr, W, bias, Out, SCL)                                              \
  {                                                                                   \
    bf16x8 afr[8];                                                                    \
    _Pragma("unroll") for (int ks = 0; ks < 8; ++ks)                                  \
        afr[ks] = *(const bf16x8*)&Sarr[w * 16 + cl][ks * 32 + g * 8];                \
    _Pragma("unroll") for (int ct = 0; ct < 8; ++ct) {                                \
      f32x4 acc = {0.f, 0.f, 0.f, 0.f};                                               \
      _Pragma("unroll") for (int ks = 0; ks < 8; ++ks) {                              \
        bf16x8 bb = *(const bf16x8*)&W[(size_t)(ct * 16 + cl) * C + ks * 32 + g * 8]; \
        acc = mfma16(afr[ks], bb, acc);                                               \
      }                                                                               \
      float bv = bias[ct * 16 + cl] * (SCL);                                          \
      _Pragma("unroll") for (int r = 0; r < 4; ++r) {                                 \
        int tok = n0 + w * 16 + g * 4 + r;                                            \
        Out[((size_t)b * N + tok) * CI + ct * 16 + cl] = f2bf(acc[r] + bv);           \
      }                                                                               \
    }                                                                                 \
  }

  PROJ_QK(xT, Wq, qb, Qb, LOG2E)
  PROJ_QK(rT, Wk, kb, Kb, 1.0f)
#undef PROJ_QK

  #pragma unroll
  for (int rt = 0; rt < 2; ++rt) {
    bf16x8 aw[8];
    #pragma unroll
    for (int ks = 0; ks < 8; ++ks)
      aw[ks] = *(const bf16x8*)&Wv[(size_t)(w * 32 + rt * 16 + cl) * C + ks * 32 + g * 8];
    #pragma unroll
    for (int ct = 0; ct < 4; ++ct) {
      f32x4 acc = {0.f, 0.f, 0.f, 0.f};
      #pragma unroll
      for (int ks = 0; ks < 8; ++ks) {
        bf16x8 bb = *(const bf16x8*)&rT[ct * 16 + cl][ks * 32 + g * 8];
        acc = mfma16(aw[ks], bb, acc);
      }
      #pragma unroll
      for (int r = 0; r < 4; ++r) {
        int o = w * 32 + rt * 16 + g * 4 + r;
        Vtb[((size_t)b * CI + o) * N + n0 + ct * 16 + cl] = f2bf(acc[r] + vb[o]);
      }
    }
  }
}

// ---------------- flash attention: 64-key tiles, 2 barriers/tile -----------
// R12's attn verbatim (best measured: 53.0us, MfmaUtil 26%, FETCH 12MB).
// 32x32 MFMA, swapped QK^T, in-lane softmax, cvtpk+permlane P, 64-key
// dbuf tiles, counted vmcnt(8), 2 barriers/iter, split 4, grid 512.
template <int SPL>
__global__ __launch_bounds__(256, 2) void attn_kernel(
    const u16* __restrict__ Qb, const u16* __restrict__ Kb,
    const u16* __restrict__ Vtb, u16* __restrict__ Opart,
    float2* __restrict__ ml) {
  constexpr int KPB = N / SPL;
  constexpr int NT = KPB / 64;
  constexpr int CPX = 16 * SPL;  // blocks per XCD
  __shared__ __align__(16) u16 Klds[2][64 * 128];  // [key][ci], swizzled chunks
  __shared__ __align__(16) u16 Vlds[2][128 * 64];  // [ci][key], swizzled chunks
  const int lin = blockIdx.x;
  const int nl = (lin & 7) * CPX + (lin >> 3);
  const int qi = nl & 31;
  const int grp = nl >> 5;  // b + 4*s
  const int b = grp & 3;
  const int s = grp >> 2;
  const int q0 = qi * 128;
  const int t = threadIdx.x;
  const int w = t >> 6, lane = t & 63;
  const int hi = lane >> 5, l31 = lane & 31;

  const u16* Kg = Kb + (size_t)b * N * CI;
  const u16* Vg = Vtb + (size_t)b * CI * N;

  const int k_ss = (t & 15) ^ ((t >> 4) & 15);
  const int v_ss = (t & 7) ^ ((t >> 3) & 7);

#define STAGE_KV(bi, k0_)                                                         \
  do {                                                                            \
    _Pragma("unroll") for (int c = 0; c < 4; ++c) {                               \
      const int r = c * 16 + (t >> 4);                                            \
      gload_lds16(Kg + (size_t)((k0_) + r) * CI + k_ss * 8,                       \
                  &Klds[bi][(c * 256 + t) * 8]);                                  \
    }                                                                             \
    _Pragma("unroll") for (int c = 0; c < 4; ++c) {                               \
      const int vr = c * 32 + (t >> 3);                                           \
      gload_lds16(Vg + (size_t)vr * N + (k0_) + v_ss * 8,                         \
                  &Vlds[bi][(c * 256 + t) * 8]);                                  \
    }                                                                             \
  } while (0)

  // hoisted Q B-fragments: lane holds Q[q0+w*32+l31][ci 16m+8hi .. +7]
  const u16* Qg = Qb + ((size_t)b * N + q0 + w * 32 + l31) * CI;
  bf16x8 qf[8];
  #pragma unroll
  for (int mm = 0; mm < 8; ++mm)
    qf[mm] = *(const bf16x8*)(Qg + mm * 16 + hi * 8);
  asm volatile("s_waitcnt vmcnt(0)" ::: "memory");  // exact vmem count from here

  f32x16 oacc[4];
  #pragma unroll
  for (int ct = 0; ct < 4; ++ct)
    #pragma unroll
    for (int i = 0; i < 16; ++i) oacc[ct][i] = 0.f;
  float m_run = -1e30f, l_run = 0.f;

  const int kbeg = s * KPB;
  STAGE_KV(0, kbeg);        // 8 loads
  STAGE_KV(1, kbeg + 64);   // 8 loads

#define SOFTMAX_HALF(st, paX0, paX1)                                              \
  {                                                                               \
    float tmax = st[0];                                                           \
    _Pragma("unroll") for (int i = 1; i < 16; ++i) tmax = fmaxf(tmax, st[i]);     \
    tmax = fmaxf(tmax, __shfl_xor(tmax, 32));                                     \
    if (!__all(tmax - m_run <= 11.5f)) {                                          \
      const float mn = fmaxf(m_run, tmax);                                        \
      const float alpha = exp2fast(m_run - mn);                                   \
      m_run = mn;                                                                 \
      l_run *= alpha;                                                             \
      _Pragma("unroll") for (int reg = 0; reg < 16; ++reg) {                      \
        float ar = __shfl(alpha, (reg & 3) + 8 * (reg >> 2) + 4 * hi);            \
        oacc[0][reg] *= ar; oacc[1][reg] *= ar;                                   \
        oacc[2][reg] *= ar; oacc[3][reg] *= ar;                                   \
      }                                                                           \
    }                                                                             \
    float p[16], ls = 0.f;                                                        \
    _Pragma("unroll") for (int i = 0; i < 16; ++i) {                              \
      p[i] = exp2fast(st[i] - m_run);                                             \
      ls += p[i];                                                                 \
    }                                                                             \
    ls += __shfl_xor(ls, 32);                                                     \
    l_run += ls;                                                                  \
    uint32_t d0 = cvtpk(p[0], p[1]),   e0 = cvtpk(p[4], p[5]);                    \
    uint32_t d1 = cvtpk(p[2], p[3]),   e1 = cvtpk(p[6], p[7]);                    \
    uint32_t d2 = cvtpk(p[8], p[9]),   e2 = cvtpk(p[12], p[13]);                  \
    uint32_t d3 = cvtpk(p[10], p[11]), e3 = cvtpk(p[14], p[15]);                  \
    plswap(d0, e0); plswap(d1, e1); plswap(d2, e2); plswap(d3, e3);               \
    u32x4 pw0 = {d0, d1, e0, e1};                                                 \
    u32x4 pw1 = {d2, d3, e2, e3};                                                 \
    paX0 = __builtin_bit_cast(bf16x8, pw0);                                       \
    paX1 = __builtin_bit_cast(bf16x8, pw1);                                       \
  }

  int buf = 0;
  for (int tt = 0; tt < NT; ++tt) {
    asm volatile("s_waitcnt vmcnt(8)" ::: "memory");
    __builtin_amdgcn_s_barrier();
    const int knext = kbeg + ((tt + 2 < NT) ? tt + 2 : tt) * 64;  // dummy tail restage

    // ---- half A key-frags (keys 0..31 of tile) ----
    bf16x8 kfA[8];
    #pragma unroll
    for (int mm = 0; mm < 8; ++mm)
      kfA[mm] = *(const bf16x8*)&Klds[buf][l31 * 128 + ((((mm << 1) | hi) ^ (l31 & 15)) & 15) * 8];
    asm volatile("s_waitcnt lgkmcnt(0)" ::: "memory");
    __builtin_amdgcn_sched_barrier(0);

    // ---- QK0 ----
    f32x16 st0;
    #pragma unroll
    for (int i = 0; i < 16; ++i) st0[i] = 0.f;
    __builtin_amdgcn_s_setprio(1);
    #pragma unroll
    for (int mm = 0; mm < 8; ++mm) st0 = mfma32(kfA[mm], qf[mm], st0);
    __builtin_amdgcn_s_setprio(0);

    // ---- softmax A -> paA ----
    bf16x8 paA0, paA1;
    SOFTMAX_HALF(st0, paA0, paA1)

    // ---- half B key-frags + half A value-frags ----
    bf16x8 kfB[8];
    #pragma unroll
    for (int mm = 0; mm < 8; ++mm)
      kfB[mm] = *(const bf16x8*)&Klds[buf][(32 + l31) * 128 + ((((mm << 1) | hi) ^ (l31 & 15)) & 15) * 8];
    bf16x8 vfA[4][2];
    #pragma unroll
    for (int ct = 0; ct < 4; ++ct)
      #pragma unroll
      for (int ks = 0; ks < 2; ++ks)
        vfA[ct][ks] = *(const bf16x8*)
            &Vlds[buf][(32 * ct + l31) * 64 + ((((ks << 1) | hi) ^ (l31 & 7)) & 7) * 8];
    asm volatile("s_waitcnt lgkmcnt(0)" ::: "memory");
    __builtin_amdgcn_sched_barrier(0);

    // ---- MFMA cluster: PV0 + QK1 ----
    f32x16 st1;
    #pragma unroll
    for (int i = 0; i < 16; ++i) st1[i] = 0.f;
    __builtin_amdgcn_s_setprio(1);
    #pragma unroll
    for (int ct = 0; ct < 4; ++ct) {
      oacc[ct] = mfma32(paA0, vfA[ct][0], oacc[ct]);
      oacc[ct] = mfma32(paA1, vfA[ct][1], oacc[ct]);
    }
    #pragma unroll
    for (int mm = 0; mm < 8; ++mm) st1 = mfma32(kfB[mm], qf[mm], st1);
    __builtin_amdgcn_s_setprio(0);

    // ---- softmax B -> paB ----
    bf16x8 paB0, paB1;
    SOFTMAX_HALF(st1, paB0, paB1)

    // ---- half B value-frags (keys 32..63 -> chunks 4..7) ----
    bf16x8 vfB[4][2];
    #pragma unroll
    for (int ct = 0; ct < 4; ++ct)
      #pragma unroll
      for (int ks = 0; ks < 2; ++ks)
        vfB[ct][ks] = *(const bf16x8*)
            &Vlds[buf][(32 * ct + l31) * 64 + (((4 + ((ks << 1) | hi)) ^ (l31 & 7)) & 7) * 8];
    asm volatile("s_waitcnt lgkmcnt(0)" ::: "memory");
    __builtin_amdgcn_sched_barrier(0);
    __builtin_amdgcn_s_barrier();     // all reads of buf done -> overwrite ok
    STAGE_KV(buf, knext);             // 8 loads for tile tt+2

    // ---- PV1 ----
    __builtin_amdgcn_s_setprio(1);
    #pragma unroll
    for (int ct = 0; ct < 4; ++ct) {
      oacc[ct] = mfma32(paB0, vfB[ct][0], oacc[ct]);
      oacc[ct] = mfma32(paB1, vfB[ct][1], oacc[ct]);
    }
    __builtin_amdgcn_s_setprio(0);

    buf ^= 1;
  }
#undef STAGE_KV
#undef SOFTMAX_HALF
  asm volatile("s_waitcnt vmcnt(0)" ::: "memory");  // drain dummy restages

  // epilogue: normalized partial O + (m,l); oacc[ct][reg] is
  // O[q = q0+w*32+crow(reg,hi)][ci = 32ct+l31]
  const float inv = 1.0f / l_run;
  #pragma unroll
  for (int reg = 0; reg < 16; ++reg) {
    const int ql = (reg & 3) + 8 * (reg >> 2) + 4 * hi;
    const float invr = __shfl(inv, ql);
    const int q = q0 + w * 32 + ql;
    #pragma unroll
    for (int ct = 0; ct < 4; ++ct)
      Opart[(((size_t)(s * BATCH + b)) * N + q) * CI + 32 * ct + l31] =
          f2bf(oacc[ct][reg] * invr);
  }
  if (lane < 32) {
    const int q = q0 + w * 32 + lane;
    ml[(size_t)(s * BATCH + b) * N + q] = make_float2(m_run, l_run);
  }
}

// ---------------- fused combine + output projection + residual -------------
template <int NS>
__global__ __launch_bounds__(256) void outproj_kernel(
    const u16* __restrict__ Opart, const float2* __restrict__ ml,
    const u16* __restrict__ Wo, const float* __restrict__ obias,
    const float* __restrict__ rgbd, float* __restrict__ out) {
  __shared__ __align__(16) u16 ObL[64][CI + 8];
  const int b = blockIdx.y;
  const int n0 = blockIdx.x * 64;
  const int t = threadIdx.x;

  // ---- phase A: split-K combine into LDS ----
  #pragma unroll
  for (int i = 0; i < 4; ++i) {
    const int idx = t + i * 256;          // over 64 rows x 16 ci-chunks
    const int row_l = idx >> 4, ci8 = idx & 15;
    const size_t row = (size_t)b * N + n0 + row_l;
    float2 sv[NS];
    float M = -1e30f;
    #pragma unroll
    for (int sp = 0; sp < NS; ++sp) {
      sv[sp] = ml[(size_t)sp * BATCH * N + row];
      M = fmaxf(M, sv[sp].x);
    }
    float wv[NS], wsum = 0.f;
    #pragma unroll
    for (int sp = 0; sp < NS; ++sp) {
      wv[sp] = sv[sp].y * exp2fast(sv[sp].x - M);
      wsum += wv[sp];
    }
    const float invL = 1.0f / wsum;
    float acc[8];
    #pragma unroll
    for (int j = 0; j < 8; ++j) acc[j] = 0.f;
    #pragma unroll
    for (int sp = 0; sp < NS; ++sp) {
      const float wsc = wv[sp] * invL;
      bf16x8 v = *(const bf16x8*)&Opart[((size_t)sp * BATCH * N + row) * CI + ci8 * 8];
      #pragma unroll
      for (int j = 0; j < 8; ++j) acc[j] += wsc * bf2f((u16)v[j]);
    }
    bf16x8 o;
    #pragma unroll
    for (int j = 0; j < 8; ++j) o[j] = (short)f2bf(acc[j]);
    *(bf16x8*)&ObL[row_l][ci8 * 8] = o;
  }
  __syncthreads();

  // ---- phase B: out-projection MFMA + bias + residual ----
  const int w = t >> 6, lane = t & 63, g = lane >> 4, cl = lane & 15;
  f32x4 acc[4][4];
  #pragma unroll
  for (int i = 0; i < 4; ++i)
    #pragma unroll
    for (int j = 0; j < 4; ++j) acc[i][j] = {0.f, 0.f, 0.f, 0.f};

  #pragma unroll
  for (int ks = 0; ks < 4; ++ks) {
    bf16x8 bo[4];
    #pragma unroll
    for (int ct = 0; ct < 4; ++ct)
      bo[ct] = *(const bf16x8*)&ObL[ct * 16 + cl][ks * 32 + g * 8];
    #pragma unroll
    for (int rt = 0; rt < 4; ++rt) {
      bf16x8 aw = *(const bf16x8*)&Wo[(size_t)(w * 64 + rt * 16 + cl) * CI + ks * 32 + g * 8];
      #pragma unroll
      for (int ct = 0; ct < 4; ++ct) acc[rt][ct] = mfma16(aw, bo[ct], acc[rt][ct]);
    }
  }
  #pragma unroll
  for (int rt = 0; rt < 4; ++rt) {
    #pragma unroll
    for (int r = 0; r < 4; ++r) {
      const int o = w * 64 + rt * 16 + g * 4 + r;
      const float bb = obias[o];
      #pragma unroll
      for (int ct = 0; ct < 4; ++ct) {
        size_t idx = ((size_t)b * C + o) * N + n0 + ct * 16 + cl;
        out[idx] = rgbd[idx] + bb + acc[rt][ct][r];
      }
    }
  }
}

// ---------------- launch ----------------------------------------------------
extern "C" void kernel_launch(void* const* d_in, const int* in_sizes, int n_in,
                              void* d_out, int out_size, void* d_ws, size_t ws_size,
                              hipStream_t stream) {
  (void)in_sizes; (void)n_in; (void)out_size; (void)ws_size;
  const float* rgbd = (const float*)d_in[0];
  const float* x    = (const float*)d_in[1];
  const float* q_w  = (const float*)d_in[2];
  const float* q_b  = (const float*)d_in[3];
  const float* k_w  = (const float*)d_in[4];
  const float* k_b  = (const float*)d_in[5];
  const float* v_w  = (const float*)d_in[6];
  const float* v_b  = (const float*)d_in[7];
  const float* o_w  = (const float*)d_in[8];
  const float* o_b  = (const float*)d_in[9];
  float* out = (float*)d_out;

  char* ws = (char*)d_ws;
  const size_t MB = 1024 * 1024;
  const size_t szQKV = (size_t)BATCH * N * CI * sizeof(u16);  // 4 MB each
  u16* Qb  = (u16*)(ws);                      // 0..4MB
  u16* Kb  = (u16*)(ws + szQKV);              // 4..8MB
  u16* Vtb = (u16*)(ws + 2 * szQKV);          // 8..12MB
  u16* Wq  = (u16*)(ws + 3 * szQKV);          // 12..12.25MB
  u16* Wk  = Wq + (size_t)CI * C;
  u16* Wv  = Wk + (size_t)CI * C;
  u16* Wo  = Wv + (size_t)CI * C;
  u16* Opart = (u16*)(ws + 13 * MB);          // 13..29MB (SPLIT*4MB)
  float2* ml = (float2*)(ws + 29 * MB);       // 29..29.5MB

  cvt_w<<<dim3((C * CI) / 256), 256, 0, stream>>>(q_w, k_w, v_w, o_w, Wq, Wk, Wv, Wo);
  proj_kernel<<<dim3(N / 64, BATCH), 256, 0, stream>>>(x, rgbd, Wq, Wk, Wv,
                                                       q_b, k_b, v_b, Qb, Kb, Vtb);
  attn_kernel<SPLIT><<<dim3(128 * SPLIT), 256, 0, stream>>>(Qb, Kb, Vtb, Opart, ml);
  outproj_kernel<SPLIT><<<dim3(N / 64, BATCH), 256, 0, stream>>>(Opart, ml, Wo, o_b, rgbd, out);
}